// Round 5
// baseline (39.934 us; speedup 1.0000x reference)
//
#include <hip/hip_runtime.h>
#include <hip/hip_bf16.h>

#define EPS 1e-5f

typedef __bf16 v8bf __attribute__((ext_vector_type(8)));
typedef __bf16 v4bf __attribute__((ext_vector_type(4)));
typedef float  v4f  __attribute__((ext_vector_type(4)));

// ---------------------------------------------------------------------------
// Weight transform: per-tap MFMA B-fragments (unchanged).
// fb1: [ky(5)][nt(2)][lane(64)][8]  k=(dx,ic): dx=k>>2 (0..7), ic=k&3; zero pad
// fb2: [tap(25)][nt(2)][lane(64)][8]  k = ic (0..31)
// fb3: [tap(25)][nt(4)][lane(64)][8]  k = ic (0..31)
// B elem: lane l, reg j -> B[k=(l>>4)*8+j][n=l&15]
// ---------------------------------------------------------------------------
__global__ void k_wtrans(const float* __restrict__ w1, const float* __restrict__ w2,
                         const float* __restrict__ w3,
                         __hip_bfloat16* __restrict__ fb1, __hip_bfloat16* __restrict__ fb2,
                         __hip_bfloat16* __restrict__ fb3)
{
    int idx = blockIdx.x * 256 + threadIdx.x;
    if (idx < 640) {                               // fb1: 5*2*64
        int lane = idx & 63, fi = idx >> 6;        // fi = ky*2 + nt
        int ky = fi >> 1, nt = fi & 1;
        int oc = nt * 16 + (lane & 15), k0 = (lane >> 4) * 8;
        __hip_bfloat16* dst = fb1 + idx * 8;
        #pragma unroll
        for (int j = 0; j < 8; ++j) {
            int k = k0 + j, dx = k >> 2, ic = k & 3;
            float val = (dx < 5 && ic < 3) ? w1[oc * 75 + ic * 25 + ky * 5 + dx] : 0.f;
            dst[j] = __float2bfloat16(val);
        }
    } else if (idx < 640 + 3200) {                 // fb2: 25*2*64
        int k2 = idx - 640;
        int lane = k2 & 63, fi = k2 >> 6;          // fi = tap*2 + nt
        int tap = fi >> 1, nt = fi & 1;
        int oc = nt * 16 + (lane & 15), ic0 = (lane >> 4) * 8;
        __hip_bfloat16* dst = fb2 + k2 * 8;
        #pragma unroll
        for (int j = 0; j < 8; ++j)
            dst[j] = __float2bfloat16(w2[oc * 800 + (ic0 + j) * 25 + tap]);
    } else if (idx < 640 + 3200 + 6400) {          // fb3: 25*4*64
        int k3 = idx - 3840;
        int lane = k3 & 63, fi = k3 >> 6;          // fi = tap*4 + nt
        int tap = fi >> 2, nt = fi & 3;
        int oc = nt * 16 + (lane & 15), ic0 = (lane >> 4) * 8;
        __hip_bfloat16* dst = fb3 + k3 * 8;
        #pragma unroll
        for (int j = 0; j < 8; ++j)
            dst[j] = __float2bfloat16(w3[oc * 800 + (ic0 + j) * 25 + tap]);
    }
}

// ---------------------------------------------------------------------------
// Fused whole-network kernel, 512 threads / 8 waves per block, 1 image/block.
// Work split per phase (vs R4's 4-wave version, per-wave chain halved):
//   conv1: wave = (prg 0..3)*2 + nt;  4 pooled-row iters x 1 nt each
//   conv2: wave = (wgrp 0..3)*2 + nt; 2 pooled rows x 1 nt each
//   conv3: wave = (nt 0..3)*2 + mh;   2 M-tiles x 1 nt each
//   FC:    wave = oc (stride 8)
// B-fragment loads register-double-buffered (next group loads issued before
// current group's MFMAs) to hide L2 latency.
// LDS pool (43840 B, phase-aliased):
//   xs2 [20][20][40] bf16 @ 0      conv1-out / conv2-in
//   xs1 [37][40][4]  bf16 @ 32000  conv1-in staging
//   xs3 [12][12][40] bf16 @ 32000  conv2-out / conv3-in (overwrites xs1)
//   fin [1024]       f32  @ 0      conv3-out / fc-in (overwrites xs2)
// ---------------------------------------------------------------------------
__global__ __launch_bounds__(512, 4) void k_fused(
    const float* __restrict__ x,
    const __hip_bfloat16* __restrict__ fb1,
    const __hip_bfloat16* __restrict__ fb2,
    const __hip_bfloat16* __restrict__ fb3,
    const float* __restrict__ w4,
    const float* __restrict__ g1, const float* __restrict__ b1,
    const float* __restrict__ m1, const float* __restrict__ v1,
    const float* __restrict__ g2, const float* __restrict__ b2,
    const float* __restrict__ m2, const float* __restrict__ v2,
    const float* __restrict__ g3, const float* __restrict__ b3,
    const float* __restrict__ m3, const float* __restrict__ v3,
    const float* __restrict__ g4, const float* __restrict__ b4,
    const float* __restrict__ m4, const float* __restrict__ v4,
    float* __restrict__ out)
{
    __shared__ __align__(16) unsigned char pool[43840];
    __shared__ float sc1[32], bi1[32], sc2[32], bi2[32], sc3[64], bi3[64];

    __hip_bfloat16 (*xs2)[20][40] = (__hip_bfloat16(*)[20][40])pool;
    __hip_bfloat16 (*xs1)[40][4]  = (__hip_bfloat16(*)[40][4])(pool + 32000);
    __hip_bfloat16 (*xs3)[12][40] = (__hip_bfloat16(*)[12][40])(pool + 32000);
    float* fin = (float*)pool;

    const int img = blockIdx.x, t = threadIdx.x;
    const int lane = t & 63, wave = t >> 6;
    const int lo = lane & 15, hi = lane >> 4;

    // ---- conv1 B-frags: issue first, latency hides under zero+stage ----
    const int nt1 = wave & 1;
    v8bf bw[5];
    #pragma unroll
    for (int ky = 0; ky < 5; ++ky)
        bw[ky] = *(const v8bf*)(fb1 + ((ky * 2 + nt1) * 64 + lane) * 8);

    // ---- init: zero pool, BN affine consts ----
    for (int i = t; i < 2740; i += 512) ((uint4*)pool)[i] = make_uint4(0, 0, 0, 0);
    if (t < 32) {
        float s = g1[t] * rsqrtf(v1[t] + EPS); sc1[t] = s; bi1[t] = b1[t] - m1[t] * s;
        float u = g2[t] * rsqrtf(v2[t] + EPS); sc2[t] = u; bi2[t] = b2[t] - m2[t] * u;
    }
    if (t < 64) {
        float s = g3[t] * rsqrtf(v3[t] + EPS); sc3[t] = s; bi3[t] = b3[t] - m3[t] * s;
    }
    __syncthreads();

    // ---- phase 0: stage input -> xs1 (bf16 [y][x][ic] interior) ----
    for (int i = t; i < 768; i += 512) {
        float4 val = *(const float4*)(x + (size_t)img * 3072 + i * 4);
        int ic = i >> 8, rem = i & 255;
        int y = rem >> 3, xx = (rem & 7) * 4;
        xs1[y + 2][xx + 2][ic] = __float2bfloat16(val.x);
        xs1[y + 2][xx + 3][ic] = __float2bfloat16(val.y);
        xs1[y + 2][xx + 4][ic] = __float2bfloat16(val.z);
        xs1[y + 2][xx + 5][ic] = __float2bfloat16(val.w);
    }
    __syncthreads();

    // ---- phase 1: conv1 (3->32), K=(dx,ic) packing -> xs2 interior ----
    {
        const int prg = wave >> 1;             // 0..3
        #pragma unroll
        for (int pi = 0; pi < 4; ++pi) {
            const int pr = prg + pi * 4;       // pooled row 0..15
            const int y0 = 2 * pr;
            v4f acc[2][2];                     // [yb][xh]
            #pragma unroll
            for (int a0 = 0; a0 < 2; ++a0)
                #pragma unroll
                for (int a1 = 0; a1 < 2; ++a1)
                    acc[a0][a1] = (v4f){0.f, 0.f, 0.f, 0.f};

            #pragma unroll
            for (int xh = 0; xh < 2; ++xh) {
                const int xx = xh * 16 + lo + hi * 2;
                v8bf av[6];
                #pragma unroll
                for (int r = 0; r < 6; ++r) {
                    v4bf lo4 = *(const v4bf*)&xs1[y0 + r][xx][0];
                    v4bf hi4 = *(const v4bf*)&xs1[y0 + r][xx + 1][0];
                    av[r] = __builtin_shufflevector(lo4, hi4, 0, 1, 2, 3, 4, 5, 6, 7);
                }
                #pragma unroll
                for (int ky = 0; ky < 5; ++ky) {
                    acc[0][xh] = __builtin_amdgcn_mfma_f32_16x16x32_bf16(av[ky],     bw[ky], acc[0][xh], 0, 0, 0);
                    acc[1][xh] = __builtin_amdgcn_mfma_f32_16x16x32_bf16(av[ky + 1], bw[ky], acc[1][xh], 0, 0, 0);
                }
            }
            const int oc = nt1 * 16 + lo;
            const float s = sc1[oc], bb = bi1[oc];
            #pragma unroll
            for (int xh = 0; xh < 2; ++xh) {
                float u0 = fmaxf(fmaf(acc[0][xh][0], s, bb), 0.f);
                float u1 = fmaxf(fmaf(acc[0][xh][1], s, bb), 0.f);
                float u2 = fmaxf(fmaf(acc[0][xh][2], s, bb), 0.f);
                float u3 = fmaxf(fmaf(acc[0][xh][3], s, bb), 0.f);
                float q0 = fmaxf(fmaf(acc[1][xh][0], s, bb), 0.f);
                float q1 = fmaxf(fmaf(acc[1][xh][1], s, bb), 0.f);
                float q2 = fmaxf(fmaf(acc[1][xh][2], s, bb), 0.f);
                float q3 = fmaxf(fmaf(acc[1][xh][3], s, bb), 0.f);
                float p0 = fminf(0.25f * (u0 + u1 + q0 + q1), 1.f);
                float p1 = fminf(0.25f * (u2 + u3 + q2 + q3), 1.f);
                const int px = xh * 8 + hi * 2;
                xs2[pr + 2][px + 2][oc] = __float2bfloat16(p0);
                xs2[pr + 2][px + 3][oc] = __float2bfloat16(p1);
            }
        }
    }
    __syncthreads();

    // ---- zero xs3 region (overwrites dead xs1) ----
    {
        uint4* p3 = (uint4*)(pool + 32000);
        for (int i = t; i < 720; i += 512) p3[i] = make_uint4(0, 0, 0, 0);
    }
    __syncthreads();

    // ---- phase 2: conv2 (32->32) -> xs3 interior; kx-outer, dbuf B-frags ----
    {
        const int nt = wave & 1, wgrp = wave >> 1;   // wgrp 0..3
        v4f acc[2][2];                               // [rpi][yb]
        #pragma unroll
        for (int a0 = 0; a0 < 2; ++a0)
            #pragma unroll
            for (int a1 = 0; a1 < 2; ++a1)
                acc[a0][a1] = (v4f){0.f, 0.f, 0.f, 0.f};

        v8bf bf[5];
        #pragma unroll
        for (int ky = 0; ky < 5; ++ky)
            bf[ky] = *(const v8bf*)(fb2 + ((ky * 5 + 0) * 2 + nt) * 512 + lane * 8);

        #pragma unroll
        for (int kx = 0; kx < 5; ++kx) {
            v8bf bfn[5];
            if (kx < 4) {
                #pragma unroll
                for (int ky = 0; ky < 5; ++ky)
                    bfn[ky] = *(const v8bf*)(fb2 + ((ky * 5 + kx + 1) * 2 + nt) * 512 + lane * 8);
            }
            v8bf av[8];
            #pragma unroll
            for (int r = 0; r < 8; ++r)
                av[r] = *(const v8bf*)&xs2[wgrp * 4 + r][lo + kx][hi * 8];
            #pragma unroll
            for (int ky = 0; ky < 5; ++ky) {
                acc[0][0] = __builtin_amdgcn_mfma_f32_16x16x32_bf16(av[ky],     bf[ky], acc[0][0], 0, 0, 0);
                acc[0][1] = __builtin_amdgcn_mfma_f32_16x16x32_bf16(av[ky + 1], bf[ky], acc[0][1], 0, 0, 0);
                acc[1][0] = __builtin_amdgcn_mfma_f32_16x16x32_bf16(av[ky + 2], bf[ky], acc[1][0], 0, 0, 0);
                acc[1][1] = __builtin_amdgcn_mfma_f32_16x16x32_bf16(av[ky + 3], bf[ky], acc[1][1], 0, 0, 0);
            }
            if (kx < 4) {
                #pragma unroll
                for (int ky = 0; ky < 5; ++ky) bf[ky] = bfn[ky];
            }
        }

        const int oc = nt * 16 + lo;
        const float s = sc2[oc], bb = bi2[oc];
        #pragma unroll
        for (int rpi = 0; rpi < 2; ++rpi) {
            const int rp = wgrp * 2 + rpi;
            float u0 = fmaxf(fmaf(acc[rpi][0][0], s, bb), 0.f);
            float u1 = fmaxf(fmaf(acc[rpi][0][1], s, bb), 0.f);
            float u2 = fmaxf(fmaf(acc[rpi][0][2], s, bb), 0.f);
            float u3 = fmaxf(fmaf(acc[rpi][0][3], s, bb), 0.f);
            float q0 = fmaxf(fmaf(acc[rpi][1][0], s, bb), 0.f);
            float q1 = fmaxf(fmaf(acc[rpi][1][1], s, bb), 0.f);
            float q2 = fmaxf(fmaf(acc[rpi][1][2], s, bb), 0.f);
            float q3 = fmaxf(fmaf(acc[rpi][1][3], s, bb), 0.f);
            float p0 = fminf(0.25f * (u0 + u1 + q0 + q1), 1.f);
            float p1 = fminf(0.25f * (u2 + u3 + q2 + q3), 1.f);
            xs3[rp + 2][hi * 2 + 2][oc] = __float2bfloat16(p0);
            xs3[rp + 2][hi * 2 + 3][oc] = __float2bfloat16(p1);
        }
    }
    __syncthreads();

    // ---- phase 3: conv3 (32->64) -> fin; ky-grouped, dbuf B-frags ----
    {
        const int nt = wave >> 1, mh = wave & 1;
        const int oc = nt * 16 + lo;
        const int ya0 = lo >> 3, xa = lo & 7;
        v4f acc[2];
        #pragma unroll
        for (int q = 0; q < 2; ++q) acc[q] = (v4f){0.f, 0.f, 0.f, 0.f};

        v8bf bf[5];
        #pragma unroll
        for (int kx = 0; kx < 5; ++kx)
            bf[kx] = *(const v8bf*)(fb3 + ((0 * 5 + kx) * 4 + nt) * 512 + lane * 8);

        #pragma unroll
        for (int ky = 0; ky < 5; ++ky) {
            v8bf bfn[5];
            if (ky < 4) {
                #pragma unroll
                for (int kx = 0; kx < 5; ++kx)
                    bfn[kx] = *(const v8bf*)(fb3 + (((ky + 1) * 5 + kx) * 4 + nt) * 512 + lane * 8);
            }
            #pragma unroll
            for (int kx = 0; kx < 5; ++kx) {
                #pragma unroll
                for (int mi = 0; mi < 2; ++mi) {
                    const int mt = mh * 2 + mi;
                    v8bf av = *(const v8bf*)&xs3[2 * mt + ya0 + ky][xa + kx][hi * 8];
                    acc[mi] = __builtin_amdgcn_mfma_f32_16x16x32_bf16(av, bf[kx], acc[mi], 0, 0, 0);
                }
            }
            if (ky < 4) {
                #pragma unroll
                for (int kx = 0; kx < 5; ++kx) bf[kx] = bfn[kx];
            }
        }

        const float s = sc3[oc], bb = bi3[oc];
        const int xb = (hi & 1) * 2;
        #pragma unroll
        for (int mi = 0; mi < 2; ++mi) {
            const int mt = mh * 2 + mi;
            float v0 = fmaxf(fmaf(acc[mi][0], s, bb), 0.f);
            float v1 = fmaxf(fmaf(acc[mi][1], s, bb), 0.f);
            float v2 = fmaxf(fmaf(acc[mi][2], s, bb), 0.f);
            float v3 = fmaxf(fmaf(acc[mi][3], s, bb), 0.f);
            float s01 = v0 + v1, s23 = v2 + v3;
            float o01 = __shfl_xor(s01, 32);
            float o23 = __shfl_xor(s23, 32);
            float p0 = fminf(0.25f * (s01 + o01), 1.f);
            float p1 = fminf(0.25f * (s23 + o23), 1.f);
            if (hi < 2) {
                fin[oc * 16 + mt * 4 + xb]     = p0;
                fin[oc * 16 + mt * 4 + xb + 1] = p1;
            }
        }
    }
    __syncthreads();

    // ---- phase 4: FC 1024->10 + BN1d ----
    {
        for (int oc = wave; oc < 10; oc += 8) {
            const float4* wp = (const float4*)(w4 + oc * 1024);
            const float4* fp = (const float4*)fin;
            float acc0 = 0.f, acc1 = 0.f;
            #pragma unroll
            for (int ch = 0; ch < 4; ++ch) {
                float4 a = fp[ch * 64 + lane];
                float4 w = wp[ch * 64 + lane];
                acc0 = fmaf(a.x, w.x, acc0); acc1 = fmaf(a.y, w.y, acc1);
                acc0 = fmaf(a.z, w.z, acc0); acc1 = fmaf(a.w, w.w, acc1);
            }
            float acc = acc0 + acc1;
            acc += __shfl_xor(acc, 1);
            acc += __shfl_xor(acc, 2);
            acc += __shfl_xor(acc, 4);
            acc += __shfl_xor(acc, 8);
            acc += __shfl_xor(acc, 16);
            acc += __shfl_xor(acc, 32);
            if (lane == 0) {
                float s = g4[oc] * rsqrtf(v4[oc] + EPS);
                out[img * 10 + oc] = acc * s + (b4[oc] - m4[oc] * s);
            }
        }
    }
}

extern "C" void kernel_launch(void* const* d_in, const int* in_sizes, int n_in,
                              void* d_out, int out_size, void* d_ws, size_t ws_size,
                              hipStream_t stream) {
    const float* x  = (const float*)d_in[0];
    const float* w1 = (const float*)d_in[1];
    const float* g1 = (const float*)d_in[2];
    const float* b1 = (const float*)d_in[3];
    const float* m1 = (const float*)d_in[4];
    const float* v1 = (const float*)d_in[5];
    const float* w2 = (const float*)d_in[6];
    const float* g2 = (const float*)d_in[7];
    const float* b2 = (const float*)d_in[8];
    const float* m2 = (const float*)d_in[9];
    const float* v2 = (const float*)d_in[10];
    const float* w3 = (const float*)d_in[11];
    const float* g3 = (const float*)d_in[12];
    const float* b3 = (const float*)d_in[13];
    const float* m3 = (const float*)d_in[14];
    const float* v3 = (const float*)d_in[15];
    const float* w4 = (const float*)d_in[16];
    const float* g4 = (const float*)d_in[17];
    const float* b4 = (const float*)d_in[18];
    const float* m4 = (const float*)d_in[19];
    const float* v4 = (const float*)d_in[20];
    float* out = (float*)d_out;

    char* base = (char*)d_ws;
    __hip_bfloat16* fb1 = (__hip_bfloat16*)base;             // 10.24 KB (pad to 16K)
    __hip_bfloat16* fb2 = (__hip_bfloat16*)(base + 16384);   // 51.2 KB
    __hip_bfloat16* fb3 = (__hip_bfloat16*)(base + 67584);   // 102.4 KB

    k_wtrans<<<40, 256, 0, stream>>>(w1, w2, w3, fb1, fb2, fb3);
    k_fused<<<1024, 512, 0, stream>>>(x, fb1, fb2, fb3, w4,
                                      g1, b1, m1, v1, g2, b2, m2, v2,
                                      g3, b3, m3, v3, g4, b4, m4, v4, out);
}